// Round 3
// baseline (30.660 us; speedup 1.0000x reference)
//
#include <hip/hip_runtime.h>

#define B_DIM 8
#define T_DIM 16
#define H_IN 500
#define W_IN 500
#define NPH 127
#define NPW 127
#define STEP 4
#define LSTR 516   // 512+4 LDS row stride: keeps transposed gathers <=2-way (free)
#define NT 512     // 512 threads = 8 waves/block, 2 blocks/CU -> 16 waves/CU

// One block per (b, q): owns output rows [8q, 8q+8). Computes them once
// (each input element read exactly once), writes the crop, and emits:
//   - full patch ph=2q            (band rows 0..7)
//   - half patch ph=2q+1, i=0..3  (band rows 4..7)
//   - half patch ph=2q-1, i=4..7  (band rows 0..3)
// Patch layout patches[b, ph*127+pw, j*8+i]: each (pw,j,half) is one float4.
__global__ __launch_bounds__(NT) void k_band(const float* __restrict__ in,
                                             const float* __restrict__ wgt,
                                             float* __restrict__ patches,
                                             float* __restrict__ crop) {
    __shared__ float lds[8 * LSTR];
    __shared__ float4 wlds[T_DIM * 4];     // weight[t][r][0..3]
    int tid = threadIdx.x;
    if (tid < T_DIM * 4) wlds[tid] = reinterpret_cast<const float4*>(wgt)[tid];

    // XCD-chunked swizzle: 512 blocks = 8 XCD * 64. orig%8 picks the XCD, so
    // map chunk orig%8 -> one b, with q consecutive inside the chunk: all
    // bands of a given b (which co-own interleaved odd-patch cachelines)
    // share that XCD's L2.
    int orig = blockIdx.x;
    int n = (orig & 7) * 64 + (orig >> 3);
    int q = n & 63;
    int b = n >> 6;
    __syncthreads();

    // ---- Phase A: compute 8 rows x 512 cols into LDS (+ crop write) ----
    #pragma unroll
    for (int k = 0; k < 2; ++k) {
        int e = tid + k * NT;                  // 0..1023 float4 slots
        int r = e >> 7;                        // band row 0..7
        int c = (e & 127) * 4;                 // col 0..508
        int h = q * 8 + r;
        float4 acc = {0.f, 0.f, 0.f, 0.f};
        if (h < H_IN && c < W_IN) {            // 500 % 4 == 0: group-exact
            const float* base = in + (size_t)b * T_DIM * (H_IN * W_IN) + h * W_IN + c;
            int hr = h & 3;
            #pragma unroll
            for (int t = 0; t < T_DIM; ++t) {
                float4 xv = *reinterpret_cast<const float4*>(base + (size_t)t * (H_IN * W_IN));
                float4 wv = wlds[t * 4 + hr];
                acc.x += xv.x * wv.x;
                acc.y += xv.y * wv.y;
                acc.z += xv.z * wv.z;
                acc.w += xv.w * wv.w;
            }
            *reinterpret_cast<float4*>(crop + ((size_t)b * H_IN + h) * W_IN + c) = acc;
        }
        *reinterpret_cast<float4*>(&lds[r * LSTR + c]) = acc;
    }
    __syncthreads();

    // ---- Phase B1: full patch ph=2q (contiguous float4 stores) ----
    {
        float* dst = patches + (((size_t)b * NPH + 2 * q) * NPW) * 64;
        for (int e4 = tid; e4 < NPW * 16; e4 += NT) {
            int i0 = (e4 & 1) * 4;
            int j  = (e4 >> 1) & 7;
            int pw = e4 >> 4;
            int col = pw * STEP + j;
            float4 v;
            v.x = lds[(i0 + 0) * LSTR + col];
            v.y = lds[(i0 + 1) * LSTR + col];
            v.z = lds[(i0 + 2) * LSTR + col];
            v.w = lds[(i0 + 3) * LSTR + col];
            reinterpret_cast<float4*>(dst)[e4] = v;
        }
    }
    // ---- Phase B2: patch ph=2q+1, i=0..3 (from band rows 4..7) ----
    if (q < 63) {
        float* dst = patches + (((size_t)b * NPH + 2 * q + 1) * NPW) * 64;
        for (int e = tid; e < NPW * 8; e += NT) {
            int j  = e & 7;
            int pw = e >> 3;
            int col = pw * STEP + j;
            float4 v;
            v.x = lds[4 * LSTR + col];
            v.y = lds[5 * LSTR + col];
            v.z = lds[6 * LSTR + col];
            v.w = lds[7 * LSTR + col];
            reinterpret_cast<float4*>(dst)[pw * 16 + j * 2] = v;
        }
    }
    // ---- Phase B3: patch ph=2q-1, i=4..7 (from band rows 0..3) ----
    if (q > 0) {
        float* dst = patches + (((size_t)b * NPH + 2 * q - 1) * NPW) * 64;
        for (int e = tid; e < NPW * 8; e += NT) {
            int j  = e & 7;
            int pw = e >> 3;
            int col = pw * STEP + j;
            float4 v;
            v.x = lds[0 * LSTR + col];
            v.y = lds[1 * LSTR + col];
            v.z = lds[2 * LSTR + col];
            v.w = lds[3 * LSTR + col];
            reinterpret_cast<float4*>(dst)[pw * 16 + j * 2 + 1] = v;
        }
    }
}

extern "C" void kernel_launch(void* const* d_in, const int* in_sizes, int n_in,
                              void* d_out, int out_size, void* d_ws, size_t ws_size,
                              hipStream_t stream) {
    const float* in  = (const float*)d_in[0];
    const float* wgt = (const float*)d_in[1];
    float* out     = (float*)d_out;
    float* patches = out;                                      // 8*16129*64 floats
    float* crop    = out + (size_t)B_DIM * NPH * NPW * 64;     // then 8*500*500

    k_band<<<B_DIM * 64, NT, 0, stream>>>(in, wgt, patches, crop);
}